// Round 1
// 245.105 us; speedup vs baseline: 1.0688x; 1.0688x over previous
//
#include <hip/hip_runtime.h>

// 3x3 conv, stride 1, pad 1, NCHW/OIHW fp32. N=16, C=32, OC=32, H=W=256.
//
// R4: cut staging overhead + hide load latency.
//  - weight image (bf16, [t9][oc] stride 36) precomputed ONCE in d_ws by a
//    36-block prep kernel; main blocks do a linear int4 copy (no divides,
//    no 9-way-conflict scatter -- that was a big slice of VALUBusy=28% and
//    of the 1.42e7 bank-conflict cycles)
//  - fp32->bf16 pack via v_cvt_pk_bf16_f32 (1 instr per 2 elems, was ~12)
//  - half1 global loads issued right after barrier #1 -> they drain at
//    barrier #2, hidden under MFMA half0 (T14 issue-early/write-late)
//  - non-temporal output stores (134 MB streaming; keep L2/L3 for x reuse)
//  - LDS layout unchanged from R3 (verified): ldsX stride 20 ush (2-way
//    free on frag reads), ldsW stride 36 ush (2-way free). 51.7KB -> 3 blk/CU.

constexpr int N_  = 16;
constexpr int C_  = 32;
constexpr int OC_ = 32;
constexpr int H_  = 256;
constexpr int W_  = 256;

constexpr int XSTR = 20;             // ushorts per wi: 32B data (16 ic) + 8B pad
constexpr int XROW = 258 * XSTR;     // ushorts per staged row (wi = w+1)
constexpr int WSTRD = 36;            // ushorts per (t9,oc): 64B data + 8B pad
constexpr int WELEMS = 9 * 32 * WSTRD;   // 10368 ushorts
constexpr int WBYTES = WELEMS * 2;       // 20736 B (= 1296 x 16B exactly)

typedef __attribute__((ext_vector_type(4)))  short short4v;
typedef __attribute__((ext_vector_type(8)))  short short8v;
typedef __attribute__((ext_vector_type(16))) float float16v;

static __device__ __forceinline__ unsigned short f2bf(float f) {
    unsigned int u = __float_as_uint(f);
    unsigned int r = (u + 0x7FFFu + ((u >> 16) & 1u)) >> 16;   // RNE
    return (unsigned short)r;
}

// one instruction: dst.lo16 = bf16(lo), dst.hi16 = bf16(hi)
static __device__ __forceinline__ unsigned cvtpk(float lo, float hi) {
    unsigned r;
    asm("v_cvt_pk_bf16_f32 %0, %1, %2" : "=v"(r) : "v"(lo), "v"(hi));
    return r;
}

static __device__ __forceinline__ short8v load8(const unsigned short* p) {
    // 8B-aligned: two ds_read_b64
    short4v lo = *(const short4v*)p;
    short4v hi = *(const short4v*)(p + 4);
    return __builtin_shufflevector(lo, hi, 0, 1, 2, 3, 4, 5, 6, 7);
}

// ---- prep: swizzled bf16 weight image, computed once per launch ----
__global__ void conv_w_prep(const float* __restrict__ wgt,
                            unsigned short* __restrict__ wp) {
    const int i = blockIdx.x * 256 + threadIdx.x;
    if (i >= OC_ * C_ * 9) return;
    const float v = wgt[i];
    const int oc  = i / 288;
    const int rem = i - oc * 288;
    const int ic  = rem / 9;
    const int t9  = rem - ic * 9;
    wp[(t9 * 32 + oc) * WSTRD + ic] = f2bf(v);
}

template<bool USE_WS>
__global__ __launch_bounds__(256, 3) void conv3x3_mfma_kernel(
    const float* __restrict__ x,     // [N][C][H][W]
    const float* __restrict__ wgt,   // [OC][C][3][3]
    const float* __restrict__ bias,  // [OC]
    const unsigned short* __restrict__ wpk,  // prepped weights (d_ws)
    float* __restrict__ out)         // [N][OC][H][W]
{
    __shared__ __align__(16) unsigned short ldsX[3 * XROW];   // 30,960 B
    __shared__ __align__(16) unsigned short ldsW[WELEMS];     // 20,736 B

    const int tid = threadIdx.x;

    // XCD-aware swizzle: 8 XCDs x 512 consecutive (n,h) rows each.
    const int id = blockIdx.x;
    const int L  = (id & 7) * 512 + (id >> 3);
    const int n  = L >> 8;
    const int h  = L & (H_ - 1);

    const int lane = tid & 63;
    const int wv   = tid >> 6;       // wave 0..3
    const int col  = lane & 31;      // A: oc; B/D: w col
    const int qd   = lane >> 5;      // k-quad select
    const int wlo  = tid & 31;       // staging: w-pair lane
    const int icp  = tid >> 5;       // staging: ic pair within half (0..7)
    const int w0a  = wv * 64;
    const int w0b  = wv * 64 + 32;
    const size_t HW = (size_t)H_ * W_;

    // ---- issue half0 x loads first (earliest possible) ----
    float2 pa[3][4], pb[3][4];
    auto load_half = [&](int half, float2 (&ra)[3][4], float2 (&rb)[3][4]) {
        const int icg = half * 16 + 2 * icp;
        const float* base = x + (size_t)(n * C_ + icg) * HW;
        #pragma unroll
        for (int r = 0; r < 3; ++r) {
            const int hy = h + r - 1;                 // block-uniform branch
            if (hy >= 0 && hy < H_) {
                const float* p0 = base + (size_t)hy * W_;
                const float* p1 = p0 + HW;
                #pragma unroll
                for (int wb = 0; wb < 4; ++wb) {
                    const int w = wb * 64 + 2 * wlo;
                    ra[r][wb] = *(const float2*)(p0 + w);
                    rb[r][wb] = *(const float2*)(p1 + w);
                }
            } else {
                #pragma unroll
                for (int wb = 0; wb < 4; ++wb) {
                    ra[r][wb] = make_float2(0.f, 0.f);
                    rb[r][wb] = make_float2(0.f, 0.f);
                }
            }
        }
    };
    load_half(0, pa, pb);

    // ---- weight stage ----
    if (USE_WS) {
        // linear copy of the prepped image: zero index math, no conflicts
        const int4* src = (const int4*)wpk;
        int4* dst = (int4*)&ldsW[0];
        #pragma unroll
        for (int i2 = 0; i2 < 6; ++i2) {
            const int idx = tid + i2 * 256;
            if (idx < WBYTES / 16) dst[idx] = src[idx];
        }
    } else {
        // fallback (no workspace): original in-kernel staging
        for (int i = tid; i < OC_ * C_ * 9; i += 256) {
            const float v = wgt[i];
            const int oc  = i / 288;
            const int rem = i - oc * 288;
            const int ic  = rem / 9;
            const int t9  = rem - ic * 9;
            ldsW[(t9 * 32 + oc) * WSTRD + ic] = f2bf(v);
        }
    }

    // ---- acc init with bias (D row = oc mapping, verified in R2) ----
    float16v acc0, acc1;
    #pragma unroll
    for (int r = 0; r < 16; ++r) {
        const float bv = bias[(r & 3) + 8 * (r >> 2) + 4 * qd];
        acc0[r] = bv;
        acc1[r] = bv;
    }

    auto write_half = [&](float2 (&ra)[3][4], float2 (&rb)[3][4]) {
        #pragma unroll
        for (int r = 0; r < 3; ++r) {
            unsigned short* dst = &ldsX[r * XROW];
            #pragma unroll
            for (int wb = 0; wb < 4; ++wb) {
                const int w = wb * 64 + 2 * wlo;
                *(unsigned*)&dst[(w + 1) * XSTR + 2 * icp] = cvtpk(ra[r][wb].x, rb[r][wb].x);
                *(unsigned*)&dst[(w + 2) * XSTR + 2 * icp] = cvtpk(ra[r][wb].y, rb[r][wb].y);
            }
        }
    };

    auto mfma_half = [&](int half) {
        #pragma unroll
        for (int kh = 0; kh < 3; ++kh) {
            #pragma unroll
            for (int kw = 0; kw < 3; ++kw) {
                const int t9 = kh * 3 + kw;
                const short8v av =
                    load8(&ldsW[(t9 * 32 + col) * WSTRD + half * 16 + qd * 8]);
                const short8v b0 =
                    load8(&ldsX[kh * XROW + (w0a + col + kw) * XSTR + qd * 8]);
                const short8v b1 =
                    load8(&ldsX[kh * XROW + (w0b + col + kw) * XSTR + qd * 8]);
                acc0 = __builtin_amdgcn_mfma_f32_32x32x16_bf16(av, b0, acc0, 0, 0, 0);
                acc1 = __builtin_amdgcn_mfma_f32_32x32x16_bf16(av, b1, acc1, 0, 0, 0);
            }
        }
    };

    // ---- pack + write half0; halo zeros (persist across both halves) ----
    write_half(pa, pb);
    if (tid < 24) {
        const int r  = tid >> 3;
        const int q  = tid & 7;
        const int wi = (q & 4) ? 257 : 0;
        const int c  = q & 3;
        *(unsigned long long*)&ldsX[r * XROW + wi * XSTR + c * 4] = 0ull;
    }
    __syncthreads();                 // X0 + W staged

    // half1 loads fly under MFMA half0; barrier #2's vmcnt(0) drains them
    load_half(1, pa, pb);
    mfma_half(0);
    __syncthreads();                 // MFMA0 readers done (and half1 loads landed)

    write_half(pa, pb);
    __syncthreads();                 // X1 staged
    mfma_half(1);

    // ---- epilogue: D row = oc, col = w; streaming stores ----
    float* outp = out + (size_t)n * OC_ * HW + (size_t)h * W_;
    #pragma unroll
    for (int r = 0; r < 16; ++r) {
        const int oc = (r & 3) + 8 * (r >> 2) + 4 * qd;
        __builtin_nontemporal_store(acc0[r], &outp[(size_t)oc * HW + w0a + col]);
        __builtin_nontemporal_store(acc1[r], &outp[(size_t)oc * HW + w0b + col]);
    }
}

extern "C" void kernel_launch(void* const* d_in, const int* in_sizes, int n_in,
                              void* d_out, int out_size, void* d_ws, size_t ws_size,
                              hipStream_t stream) {
    const float* x    = (const float*)d_in[0];
    const float* wgt  = (const float*)d_in[1];
    const float* bias = (const float*)d_in[2];
    float* out        = (float*)d_out;

    dim3 grid(N_ * H_);   // 4096 blocks: one per (n, h)
    dim3 block(256);

    if (d_ws != nullptr && ws_size >= (size_t)WBYTES) {
        unsigned short* wp = (unsigned short*)d_ws;
        conv_w_prep<<<dim3(36), dim3(256), 0, stream>>>(wgt, wp);
        conv3x3_mfma_kernel<true><<<grid, block, 0, stream>>>(x, wgt, bias, wp, out);
    } else {
        conv3x3_mfma_kernel<false><<<grid, block, 0, stream>>>(x, wgt, bias, nullptr, out);
    }
}

// Round 2
// 243.275 us; speedup vs baseline: 1.0769x; 1.0075x over previous
//
#include <hip/hip_runtime.h>

// 3x3 conv, stride 1, pad 1, NCHW/OIHW fp32. N=16, C=32, OC=32, H=W=256.
//
// R5: 2 output rows per block (512 thr, 8 waves), 2 blocks/CU.
//  - stage 4 input rows (h-1..h+2) serving 2 output rows: x staging per
//    output x0.67, weight copy / bias / barriers per output x0.5
//  - occupancy 16 waves/CU (4/SIMD), was 12 (3/SIMD)
//  - 2048 blocks = exactly 8/CU; XCD swizzle bijective, adjacent h-pairs
//    stay on one XCD for L2 row reuse
//  - unchanged from R4 (verified): LDS strides XSTR=20/WSTRD=36 (2-way-free
//    frag reads, 8B aligned), prepped bf16 weights in d_ws (linear int4
//    copy), v_cvt_pk_bf16_f32 pack, half1 loads under mfma half0,
//    non-temporal stores, D row=oc col=w epilogue mapping.

constexpr int N_  = 16;
constexpr int C_  = 32;
constexpr int OC_ = 32;
constexpr int H_  = 256;
constexpr int W_  = 256;

constexpr int XSTR = 20;             // ushorts per wi: 32B data (16 ic) + 8B pad
constexpr int XROW = 258 * XSTR;     // ushorts per staged row (wi = w+1)
constexpr int WSTRD = 36;            // ushorts per (t9,oc): 64B data + 8B pad
constexpr int WELEMS = 9 * 32 * WSTRD;   // 10368 ushorts
constexpr int WBYTES = WELEMS * 2;       // 20736 B (= 1296 x 16B exactly)

typedef __attribute__((ext_vector_type(4)))  short short4v;
typedef __attribute__((ext_vector_type(8)))  short short8v;
typedef __attribute__((ext_vector_type(16))) float float16v;

static __device__ __forceinline__ unsigned short f2bf(float f) {
    unsigned int u = __float_as_uint(f);
    unsigned int r = (u + 0x7FFFu + ((u >> 16) & 1u)) >> 16;   // RNE
    return (unsigned short)r;
}

// one instruction: dst.lo16 = bf16(lo), dst.hi16 = bf16(hi)
static __device__ __forceinline__ unsigned cvtpk(float lo, float hi) {
    unsigned r;
    asm("v_cvt_pk_bf16_f32 %0, %1, %2" : "=v"(r) : "v"(lo), "v"(hi));
    return r;
}

static __device__ __forceinline__ short8v load8(const unsigned short* p) {
    // 8B-aligned: two ds_read_b64
    short4v lo = *(const short4v*)p;
    short4v hi = *(const short4v*)(p + 4);
    return __builtin_shufflevector(lo, hi, 0, 1, 2, 3, 4, 5, 6, 7);
}

// ---- prep: swizzled bf16 weight image, computed once per launch ----
__global__ void conv_w_prep(const float* __restrict__ wgt,
                            unsigned short* __restrict__ wp) {
    const int i = blockIdx.x * 256 + threadIdx.x;
    if (i >= OC_ * C_ * 9) return;
    const float v = wgt[i];
    const int oc  = i / 288;
    const int rem = i - oc * 288;
    const int ic  = rem / 9;
    const int t9  = rem - ic * 9;
    wp[(t9 * 32 + oc) * WSTRD + ic] = f2bf(v);
}

template<bool USE_WS>
__global__ __launch_bounds__(512, 4) void conv3x3_mfma_kernel(
    const float* __restrict__ x,     // [N][C][H][W]
    const float* __restrict__ wgt,   // [OC][C][3][3]
    const float* __restrict__ bias,  // [OC]
    const unsigned short* __restrict__ wpk,  // prepped weights (d_ws)
    float* __restrict__ out)         // [N][OC][H][W]
{
    __shared__ __align__(16) unsigned short ldsX[4 * XROW];   // 41,280 B
    __shared__ __align__(16) unsigned short ldsW[WELEMS];     // 20,736 B

    const int tid = threadIdx.x;

    // XCD-aware swizzle: 2048 blocks, 8 XCDs x 256 consecutive (n, h-pair).
    const int id = blockIdx.x;
    const int L  = (id & 7) * 256 + (id >> 3);
    const int n  = L >> 7;           // image 0..15
    const int h  = (L & 127) * 2;    // output rows h, h+1

    const int lane = tid & 63;
    const int wv   = tid >> 6;       // wave 0..7
    const int rsel = wv >> 2;        // output row select (0/1)
    const int col  = lane & 31;      // A: oc; B/D: w col
    const int qd   = lane >> 5;      // k-quad select
    const int w0a  = (wv & 3) * 64;
    const int w0b  = (wv & 3) * 64 + 32;

    // staging map: thread -> (staged row r4, w-pair wlo, ic-quad icq)
    const int r4  = tid >> 7;        // staged input row 0..3 (= h-1+r4)
    const int t7  = tid & 127;
    const int wlo = t7 & 31;         // w-pair lane
    const int icq = t7 >> 5;         // 0..3 (handles ic-pairs icq and icq+4)
    const size_t HW = (size_t)H_ * W_;

    // ---- issue half0 x loads first (earliest possible) ----
    float2 a0[4], a1[4], b0r[4], b1r[4];
    auto load_half = [&](int half) {
        const int icg0 = half * 16 + 2 * icq;
        const int icg1 = half * 16 + 2 * (icq + 4);
        const int hy = h - 1 + r4;
        if (hy >= 0 && hy < H_) {
            const float* pA0 = x + ((size_t)(n * C_ + icg0) * H_ + hy) * W_;
            const float* pA1 = pA0 + HW;
            const float* pB0 = x + ((size_t)(n * C_ + icg1) * H_ + hy) * W_;
            const float* pB1 = pB0 + HW;
            #pragma unroll
            for (int wb = 0; wb < 4; ++wb) {
                const int w = wb * 64 + 2 * wlo;
                a0[wb]  = *(const float2*)(pA0 + w);
                a1[wb]  = *(const float2*)(pA1 + w);
                b0r[wb] = *(const float2*)(pB0 + w);
                b1r[wb] = *(const float2*)(pB1 + w);
            }
        } else {
            #pragma unroll
            for (int wb = 0; wb < 4; ++wb) {
                a0[wb] = a1[wb] = b0r[wb] = b1r[wb] = make_float2(0.f, 0.f);
            }
        }
    };
    load_half(0);

    // ---- weight stage ----
    if (USE_WS) {
        // linear copy of the prepped image: zero index math, no conflicts
        const int4* src = (const int4*)wpk;
        int4* dstW = (int4*)&ldsW[0];
        #pragma unroll
        for (int i2 = 0; i2 < 3; ++i2) {
            const int idx = tid + i2 * 512;
            if (idx < WBYTES / 16) dstW[idx] = src[idx];
        }
    } else {
        // fallback (no workspace): in-kernel staging
        for (int i = tid; i < OC_ * C_ * 9; i += 512) {
            const float v = wgt[i];
            const int oc  = i / 288;
            const int rem = i - oc * 288;
            const int ic  = rem / 9;
            const int t9  = rem - ic * 9;
            ldsW[(t9 * 32 + oc) * WSTRD + ic] = f2bf(v);
        }
    }

    // ---- acc init with bias (D row = oc mapping, verified in R2) ----
    float16v acc0, acc1;
    #pragma unroll
    for (int r = 0; r < 16; ++r) {
        const float bv = bias[(r & 3) + 8 * (r >> 2) + 4 * qd];
        acc0[r] = bv;
        acc1[r] = bv;
    }

    auto write_half = [&]() {
        unsigned short* dst = &ldsX[r4 * XROW];
        #pragma unroll
        for (int wb = 0; wb < 4; ++wb) {
            const int w = wb * 64 + 2 * wlo;
            *(unsigned*)&dst[(w + 1) * XSTR + 2 * icq]       = cvtpk(a0[wb].x,  a1[wb].x);
            *(unsigned*)&dst[(w + 2) * XSTR + 2 * icq]       = cvtpk(a0[wb].y,  a1[wb].y);
            *(unsigned*)&dst[(w + 1) * XSTR + 2 * (icq + 4)] = cvtpk(b0r[wb].x, b1r[wb].x);
            *(unsigned*)&dst[(w + 2) * XSTR + 2 * (icq + 4)] = cvtpk(b0r[wb].y, b1r[wb].y);
        }
    };

    auto mfma_half = [&](int half) {
        #pragma unroll
        for (int kh = 0; kh < 3; ++kh) {
            #pragma unroll
            for (int kw = 0; kw < 3; ++kw) {
                const int t9 = kh * 3 + kw;
                const short8v av =
                    load8(&ldsW[(t9 * 32 + col) * WSTRD + half * 16 + qd * 8]);
                const short8v bf0 =
                    load8(&ldsX[(rsel + kh) * XROW + (w0a + col + kw) * XSTR + qd * 8]);
                const short8v bf1 =
                    load8(&ldsX[(rsel + kh) * XROW + (w0b + col + kw) * XSTR + qd * 8]);
                acc0 = __builtin_amdgcn_mfma_f32_32x32x16_bf16(av, bf0, acc0, 0, 0, 0);
                acc1 = __builtin_amdgcn_mfma_f32_32x32x16_bf16(av, bf1, acc1, 0, 0, 0);
            }
        }
    };

    // ---- pack + write half0; halo zeros (persist across both halves) ----
    write_half();
    if (tid < 32) {
        const int r  = tid >> 3;                 // staged row 0..3
        const int q  = tid & 7;
        const int wi = (q & 4) ? 257 : 0;
        const int c  = q & 3;
        *(unsigned long long*)&ldsX[r * XROW + wi * XSTR + c * 4] = 0ull;
    }
    __syncthreads();                 // X0 + W staged

    // half1 loads fly under MFMA half0; barrier #2's vmcnt(0) drains them
    load_half(1);
    mfma_half(0);
    __syncthreads();                 // MFMA0 readers done (and half1 loads landed)

    write_half();
    __syncthreads();                 // X1 staged
    mfma_half(1);

    // ---- epilogue: D row = oc, col = w; streaming stores ----
    float* outp = out + (size_t)n * OC_ * HW + (size_t)(h + rsel) * W_;
    #pragma unroll
    for (int r = 0; r < 16; ++r) {
        const int oc = (r & 3) + 8 * (r >> 2) + 4 * qd;
        __builtin_nontemporal_store(acc0[r], &outp[(size_t)oc * HW + w0a + col]);
        __builtin_nontemporal_store(acc1[r], &outp[(size_t)oc * HW + w0b + col]);
    }
}

extern "C" void kernel_launch(void* const* d_in, const int* in_sizes, int n_in,
                              void* d_out, int out_size, void* d_ws, size_t ws_size,
                              hipStream_t stream) {
    const float* x    = (const float*)d_in[0];
    const float* wgt  = (const float*)d_in[1];
    const float* bias = (const float*)d_in[2];
    float* out        = (float*)d_out;

    dim3 grid(N_ * H_ / 2);   // 2048 blocks: one per (n, h-pair)
    dim3 block(512);

    if (d_ws != nullptr && ws_size >= (size_t)WBYTES) {
        unsigned short* wp = (unsigned short*)d_ws;
        conv_w_prep<<<dim3(36), dim3(256), 0, stream>>>(wgt, wp);
        conv3x3_mfma_kernel<true><<<grid, block, 0, stream>>>(x, wgt, bias, wp, out);
    } else {
        conv3x3_mfma_kernel<false><<<grid, block, 0, stream>>>(x, wgt, bias, nullptr, out);
    }
}